// Round 12
// baseline (150.887 us; speedup 1.0000x reference)
//
#include <hip/hip_runtime.h>
#include <hip/hip_bf16.h>
#include <math.h>

// MPDO contraction, delta-decomposed bf16 MFMA, r12 "dual-state" structure:
// each wave maintains BOTH E and F=E^T in fp32 C-layout registers. All MFMA
// operands come from register packs (permlane) -> ZERO LDS, zero barriers.
//   E' = 2E + sum_k [ a_k^T E + E b_k + a_k^T(E b_k) ]
//   F' = 2F + sum_k [ b_k^T F + F a_k + (a_k^T bf16(E b_k))^T ]
// Frag-bit reuse (A-op of X == B-op of X^T, same bits):
//   EB (pack of e) : B-op = E,        A-op = F
//   EA (pack of f) : A-op = E,        B-op = F
//   CA (ws frag)   : A-op = a^T,      B-op = a
//   CB (ws frag)   : A-op = b^T,      B-op = b
//   VB (pack of V) : B-op = bf16(V),  A-op = bf16(V)^T
// r11 lesson: wall = dependency stalls (per-SIMD VALU ~15%; 2 waves/SIMD cap);
// LDS round-trip + dep-MFMA latency dominated. This removes LDS from the chain
// and doubles independent in-wave work. MFMA 12->24/site (pipe underused).

typedef __attribute__((ext_vector_type(8)))  short short8;
typedef __attribute__((ext_vector_type(16))) float f32x16;

static __device__ inline unsigned pk2(float lo, float hi) {
    union { __hip_bfloat162 h; unsigned u; } cv;
    cv.h = __float22bfloat162_rn(make_float2(lo, hi));
    return cv.u;
}
static __device__ inline short8 mk8(unsigned u0, unsigned u1, unsigned u2, unsigned u3) {
    union { short8 v; unsigned u[4]; } r;
    r.u[0] = u0; r.u[1] = u1; r.u[2] = u2; r.u[3] = u3;
    return r.v;
}
static __device__ inline short8 S8(uint4 u) {
    union { uint4 a; short8 v; } c; c.a = u; return c.v;
}
static __device__ inline void pl32swap(unsigned& x, unsigned& y) {
    asm("v_permlane32_swap_b32 %0, %1" : "+v"(x), "+v"(y));
}
static __device__ inline f32x16 MFMA(short8 a, short8 b, f32x16 c) {
    return __builtin_amdgcn_mfma_f32_32x32x16_bf16(a, b, c, 0, 0, 0);
}
static __device__ inline f32x16 zero16() {
    f32x16 z = {0.f,0.f,0.f,0.f,0.f,0.f,0.f,0.f,0.f,0.f,0.f,0.f,0.f,0.f,0.f,0.f};
    return z;
}
// B-op pack of a C-layout state: out[h] elem e = S[16h+8hi+e][col]
static __device__ inline void packS(const float* s, short8* out) {
    #pragma unroll
    for (int h = 0; h < 2; ++h) {
        unsigned ua = pk2(s[8*h+0], s[8*h+1]);
        unsigned ub = pk2(s[8*h+2], s[8*h+3]);
        unsigned uc = pk2(s[8*h+4], s[8*h+5]);
        unsigned ud = pk2(s[8*h+6], s[8*h+7]);
        pl32swap(ua, uc); pl32swap(ub, ud);
        out[h] = mk8(ua, ub, uc, ud);
    }
}
static __device__ inline void packV(const f32x16& v, short8* out) {
    #pragma unroll
    for (int h = 0; h < 2; ++h) {
        unsigned ua = pk2(v[8*h+0], v[8*h+1]);
        unsigned ub = pk2(v[8*h+2], v[8*h+3]);
        unsigned uc = pk2(v[8*h+4], v[8*h+5]);
        unsigned ud = pk2(v[8*h+6], v[8*h+7]);
        pl32swap(ua, uc); pl32swap(ub, ud);
        out[h] = mk8(ua, ub, uc, ud);
    }
}

// ---------------- prestage: middle -> d_ws bf16 fragments (unchanged r11) ----------------
__global__ __launch_bounds__(256) void mpdo_prestage(
    const float* __restrict__ middle, unsigned* __restrict__ ws)
{
    const int site = blockIdx.x;
    const int t    = threadIdx.x;
    const int s    = t >> 7;
    const int h    = (t >> 6) & 1;
    const int hi   = (t >> 5) & 1;
    const int col  = t & 31;
    const float2* m2 = (const float2*)middle + (size_t)(site*2 + s) * 1024;
    float2 v[8];
    #pragma unroll
    for (int e = 0; e < 8; ++e) {
        const int kk = 16*h + 8*hi + e;
        float2 d = m2[kk*32 + col];
        if (kk == col) { d.x -= 1.f; d.y -= 1.f; }
        v[e] = d;
    }
    uint4 o0, o1;
    o0.x = pk2(v[0].x, v[1].x); o0.y = pk2(v[2].x, v[3].x);
    o0.z = pk2(v[4].x, v[5].x); o0.w = pk2(v[6].x, v[7].x);
    o1.x = pk2(v[0].y, v[1].y); o1.y = pk2(v[2].y, v[3].y);
    o1.z = pk2(v[4].y, v[5].y); o1.w = pk2(v[6].y, v[7].y);
    uint4* w4 = (uint4*)ws;
    const int lane_off = hi*32 + col;
    w4[((site*2 + s)*4 + 0 + h)*64 + lane_off] = o0;   // k=0
    w4[((site*2 + s)*4 + 2 + h)*64 + lane_off] = o1;   // k=1
}

// ---------------- main: dual-state, 1 wave / element, no LDS ----------------
#define SITE_BODY(CA, CB, NA, NB, SITE)                                          \
  {                                                                              \
    short8 EB[2], EA[2];                                                         \
    packS(e, EB);                                                                \
    packS(f, EA);                                                                \
    /* accP = a0^T E + a1^T E  (thirds chained later) */                         \
    f32x16 accP = MFMA(S8(CA[0]), EB[0], zero16());                              \
    accP = MFMA(S8(CA[1]), EB[1], accP);                                         \
    accP = MFMA(S8(CA[2]), EB[0], accP);                                         \
    accP = MFMA(S8(CA[3]), EB[1], accP);                                         \
    /* accQ = b0^T F + b1^T F */                                                 \
    f32x16 accQ = MFMA(S8(CB[0]), EA[0], zero16());                              \
    accQ = MFMA(S8(CB[1]), EA[1], accQ);                                         \
    accQ = MFMA(S8(CB[2]), EA[0], accQ);                                         \
    accQ = MFMA(S8(CB[3]), EA[1], accQ);                                         \
    /* V_k = E b_k (pure, for VB + e-update) */                                  \
    f32x16 V0 = MFMA(EA[0], S8(CB[0]), zero16());                                \
    V0 = MFMA(EA[1], S8(CB[1]), V0);                                             \
    f32x16 V1 = MFMA(EA[0], S8(CB[2]), zero16());                                \
    V1 = MFMA(EA[1], S8(CB[3]), V1);                                             \
    /* Gs = F a0 + F a1 (raw, for f-update) */                                   \
    f32x16 Gs = MFMA(EB[0], S8(CA[0]), zero16());                                \
    Gs = MFMA(EB[1], S8(CA[1]), Gs);                                             \
    Gs = MFMA(EB[0], S8(CA[2]), Gs);                                             \
    Gs = MFMA(EB[1], S8(CA[3]), Gs);                                             \
    /* prefetch next site's fragments */                                         \
    {                                                                            \
      const int pfi = ((SITE) < 62) ? (SITE) : 61;                               \
      const int ba = (pfi*2 + srn)*4, bb = (pfi*2 + scn)*4;                      \
      _Pragma("unroll")                                                          \
      for (int kh = 0; kh < 4; ++kh) {                                           \
        NA[kh] = w4g[(ba + kh)*64 + lane_off];                                   \
        NB[kh] = w4g[(bb + kh)*64 + lane_off];                                   \
      }                                                                          \
      const int qi = ((SITE) + 2 <= 62) ? (SITE) + 2 : 62;                       \
      srn = q[qi]; scn = q[qi + 64];                                             \
    }                                                                            \
    /* thirds: e-side a_k^T bf16(V_k); f-side its exact transpose */             \
    {                                                                            \
      short8 VB[2];                                                              \
      packV(V0, VB);                                                             \
      accP = MFMA(S8(CA[0]), VB[0], accP);                                       \
      accP = MFMA(S8(CA[1]), VB[1], accP);                                       \
      accQ = MFMA(VB[0], S8(CA[0]), accQ);                                       \
      accQ = MFMA(VB[1], S8(CA[1]), accQ);                                       \
      packV(V1, VB);                                                             \
      accP = MFMA(S8(CA[2]), VB[0], accP);                                       \
      accP = MFMA(S8(CA[3]), VB[1], accP);                                       \
      accQ = MFMA(VB[0], S8(CA[2]), accQ);                                       \
      accQ = MFMA(VB[1], S8(CA[3]), accQ);                                       \
    }                                                                            \
    /* updates */                                                                \
    _Pragma("unroll")                                                            \
    for (int r = 0; r < 16; ++r) {                                               \
      e[r] = fmaf(2.f, e[r], (accP[r] + V0[r]) + V1[r]);                         \
      f[r] = fmaf(2.f, f[r], accQ[r] + Gs[r]);                                   \
    }                                                                            \
  }

__global__ __launch_bounds__(256, 2) void mpdo_dual(
    const int*      __restrict__ qn,
    const float*    __restrict__ left,
    const float*    __restrict__ right,
    const unsigned* __restrict__ ws,
    float*          __restrict__ out,
    const int       cplx)
{
    const int t    = threadIdx.x;
    const int w    = t >> 6;
    const int lane = t & 63;
    const int hi   = lane >> 5;
    const int col  = lane & 31;
    const int elem = blockIdx.x * 4 + w;
    const int* q   = qn + (size_t)elem * 128;
    const int lane_off = hi*32 + col;
    const uint4* w4g = (const uint4*)ws;

    int rowr[16];
    #pragma unroll
    for (int r = 0; r < 16; ++r) rowr[r] = (r & 3) + 8*(r >> 2) + 4*hi;

    // init E and F = E^T (fp32 C-layout; F init = same formula, Lr/Lc swapped)
    float e[16], f[16];
    {
        const float* Lr = left + (size_t)q[0]  * 64;
        const float* Lc = left + (size_t)q[64] * 64;
        const float c0v = Lc[col*2 + 0], c1v = Lc[col*2 + 1];
        const float d0v = Lr[col*2 + 0], d1v = Lr[col*2 + 1];
        #pragma unroll
        for (int r = 0; r < 16; ++r) {
            e[r] = Lr[rowr[r]*2 + 0] * c0v + Lr[rowr[r]*2 + 1] * c1v;
            f[r] = Lc[rowr[r]*2 + 0] * d0v + Lc[rowr[r]*2 + 1] * d1v;
        }
    }

    // prologue: fragments for site 1
    uint4 CA[4], CB[4], NA[4], NB[4];
    {
        const int sr = q[1], sc = q[65];
        const int ba = sr*4, bb = sc*4;
        #pragma unroll
        for (int kh = 0; kh < 4; ++kh) {
            CA[kh] = w4g[(ba + kh)*64 + lane_off];
            CB[kh] = w4g[(bb + kh)*64 + lane_off];
        }
    }
    int srn = q[2], scn = q[66];

    #pragma unroll 1
    for (int it = 0; it < 31; ++it) {
        const int siteA = 2*it + 1;
        SITE_BODY(CA, CB, NA, NB, siteA)
        SITE_BODY(NA, NB, CA, CB, siteA + 1)
    }

    // epilogue (uses e)
    {
        const float* Rr = right + (size_t)q[63]  * 64;
        const float* Rc = right + (size_t)q[127] * 64;
        const float rc0 = Rc[col*2 + 0], rc1 = Rc[col*2 + 1];
        float part = 0.f;
        #pragma unroll
        for (int r = 0; r < 16; ++r) {
            const float re = Rr[rowr[r]*2 + 0]*rc0 + Rr[rowr[r]*2 + 1]*rc1;
            part += e[r] * re;
        }
        #pragma unroll
        for (int off = 32; off > 0; off >>= 1)
            part += __shfl_down(part, off, 64);
        if (lane == 0) {
            const float re = logf(fabsf(part));
            if (cplx) {
                out[2*elem + 0] = re;
                out[2*elem + 1] = (part < 0.f) ? 3.14159265358979323846f : 0.f;
            } else {
                out[elem] = re;
            }
        }
    }
}

// ---------------- fallback: r9 kernel (validated) if ws too small ----------------
#define EPITCH 33
__global__ __launch_bounds__(256, 2) void mpdo_mfma_fb(
    const int* __restrict__ qn, const float* __restrict__ left,
    const float* __restrict__ right, const float* __restrict__ middle,
    float* __restrict__ out, const int cplx)
{
    __shared__ unsigned mid_b[2048];
    __shared__ float    E_s[4][32*EPITCH];

    const int t = threadIdx.x, w = t >> 6, lane = t & 63;
    const int hi = lane >> 5, col = lane & 31;
    const int elem = blockIdx.x * 4 + w;
    const int* q = qn + (size_t)elem * 128;
    float* Ew = E_s[w];
    const int sp = (t >> 4) & 15, sj = t & 15, jj = sj * 2;
    const float dj = (sp == sj) ? 1.0f : 0.0f;
    const int v0 = (0 + 2*sp) * 16 + sj, v1 = (32 + 2*sp) * 16 + sj;

    int rowr[16];
    #pragma unroll
    for (int r = 0; r < 16; ++r) rowr[r] = (r & 3) + 8*(r >> 2) + 4*hi;

    float e[16];
    {
        const float* Lr = left + (size_t)q[0]  * 64;
        const float* Lc = left + (size_t)q[64] * 64;
        const float c0v = Lc[col*2 + 0], c1v = Lc[col*2 + 1];
        #pragma unroll
        for (int r = 0; r < 16; ++r)
            e[r] = Lr[rowr[r]*2 + 0] * c0v + Lr[rowr[r]*2 + 1] * c1v;
    }
    const float4* gm = (const float4*)middle;
    float4 A0 = gm[v0], A1 = gm[v0 + 16], B0 = gm[v1], B1 = gm[v1 + 16];
    int srn = q[1], scn = q[65];

    for (int site = 1; site <= 62; ++site) {
        {
            uint2* m2 = (uint2*)mid_b;
            m2[((0*16 + sp)*32 + jj) >> 1] = make_uint2(pk2(A0.x - dj, A1.x), pk2(A0.z, A1.z - dj));
            m2[((1*16 + sp)*32 + jj) >> 1] = make_uint2(pk2(A0.y - dj, A1.y), pk2(A0.w, A1.w - dj));
            m2[((2*16 + sp)*32 + jj) >> 1] = make_uint2(pk2(B0.x - dj, B1.x), pk2(B0.z, B1.z - dj));
            m2[((3*16 + sp)*32 + jj) >> 1] = make_uint2(pk2(B0.y - dj, B1.y), pk2(B0.w, B1.w - dj));
        }
        #pragma unroll
        for (int r = 0; r < 16; ++r) Ew[rowr[r]*EPITCH + col] = e[r];
        __syncthreads();
        const int sr = srn, sc = scn;
        if (site < 62) {
            const float4* gn = (const float4*)(middle + (size_t)site * 4096);
            A0 = gn[v0]; A1 = gn[v0 + 16]; B0 = gn[v1]; B1 = gn[v1 + 16];
            srn = q[site + 1]; scn = q[site + 65];
        }
        short8 aT[2][2], bF[2][2];
        #pragma unroll
        for (int k = 0; k < 2; ++k)
            #pragma unroll
            for (int h = 0; h < 2; ++h) {
                const int pa = ((sr*2 + k)*16 + 8*h + 4*hi) * 32 + col;
                aT[k][h] = mk8(mid_b[pa], mid_b[pa+32], mid_b[pa+64], mid_b[pa+96]);
                const int pb = ((sc*2 + k)*16 + 8*h + 4*hi) * 32 + col;
                bF[k][h] = mk8(mid_b[pb], mid_b[pb+32], mid_b[pb+64], mid_b[pb+96]);
            }
        short8 EA[2];
        #pragma unroll
        for (int h = 0; h < 2; ++h) {
            const int base = col*EPITCH + 16*h + 8*hi;
            EA[h] = mk8(pk2(Ew[base+0], Ew[base+1]), pk2(Ew[base+2], Ew[base+3]),
                        pk2(Ew[base+4], Ew[base+5]), pk2(Ew[base+6], Ew[base+7]));
        }
        short8 EB[2];
        packS(e, EB);
        f32x16 V0 = MFMA(EA[0], bF[0][0], zero16()); V0 = MFMA(EA[1], bF[0][1], V0);
        f32x16 V1 = MFMA(EA[0], bF[1][0], zero16()); V1 = MFMA(EA[1], bF[1][1], V1);
        f32x16 acc = MFMA(aT[0][0], EB[0], zero16());
        acc = MFMA(aT[0][1], EB[1], acc);
        acc = MFMA(aT[1][0], EB[0], acc);
        acc = MFMA(aT[1][1], EB[1], acc);
        #pragma unroll
        for (int k = 0; k < 2; ++k) {
            short8 VB[2];
            packV(k ? V1 : V0, VB);
            acc = MFMA(aT[k][0], VB[0], acc);
            acc = MFMA(aT[k][1], VB[1], acc);
        }
        #pragma unroll
        for (int r = 0; r < 16; ++r)
            e[r] = 2.0f*e[r] + acc[r] + V0[r] + V1[r];
        __syncthreads();
    }
    {
        const float* Rr = right + (size_t)q[63]  * 64;
        const float* Rc = right + (size_t)q[127] * 64;
        const float rc0 = Rc[col*2 + 0], rc1 = Rc[col*2 + 1];
        float part = 0.f;
        #pragma unroll
        for (int r = 0; r < 16; ++r)
            part += e[r] * (Rr[rowr[r]*2 + 0]*rc0 + Rr[rowr[r]*2 + 1]*rc1);
        #pragma unroll
        for (int off = 32; off > 0; off >>= 1)
            part += __shfl_down(part, off, 64);
        if (lane == 0) {
            const float re = logf(fabsf(part));
            if (cplx) { out[2*elem] = re; out[2*elem+1] = (part < 0.f) ? 3.14159265f : 0.f; }
            else      { out[elem] = re; }
        }
    }
}

extern "C" void kernel_launch(void* const* d_in, const int* in_sizes, int n_in,
                              void* d_out, int out_size, void* d_ws, size_t ws_size,
                              hipStream_t stream) {
    const int*   qn     = (const int*)  d_in[0];
    const float* left   = (const float*)d_in[1];
    const float* right  = (const float*)d_in[2];
    const float* middle = (const float*)d_in[3];
    float* out = (float*)d_out;

    const int B    = in_sizes[0] / 128;
    const int cplx = (out_size >= 2 * B) ? 1 : 0;
    const size_t need = 62ull * 8192ull;

    if (ws_size >= need) {
        mpdo_prestage<<<62, 256, 0, stream>>>(middle, (unsigned*)d_ws);
        mpdo_dual<<<B / 4, 256, 0, stream>>>(qn, left, right, (const unsigned*)d_ws,
                                             out, cplx);
    } else {
        mpdo_mfma_fb<<<B / 4, 256, 0, stream>>>(qn, left, right, middle, out, cplx);
    }
}